// Round 1
// baseline (497.741 us; speedup 1.0000x reference)
//
#include <hip/hip_runtime.h>
#include <hip/hip_bf16.h>
#include <stdint.h>

typedef __attribute__((ext_vector_type(8))) short bf16x8;
typedef __attribute__((ext_vector_type(4))) float f32x4;
typedef unsigned short u16;
typedef unsigned int u32;

#define BB 8
#define HH 8
#define LL 1024
#define DM 512
#define DH 64

__device__ __forceinline__ u16 f2bf(float f){
  u32 u = __builtin_bit_cast(u32, f);
  u32 r = u + 0x7FFFu + ((u>>16)&1u);   // RNE
  return (u16)(r>>16);
}

__device__ __forceinline__ f32x4 mfma16(bf16x8 a, bf16x8 b, f32x4 c){
  return __builtin_amdgcn_mfma_f32_16x16x32_bf16(a, b, c, 0, 0, 0);
}

// ---------------- fp32 -> bf16 convert ----------------
struct CvtArgs {
  const float* src[7];
  u16* dst[7];
  int n4[7];
};

__global__ __launch_bounds__(256) void cvt_kernel(CvtArgs a){
  int seg = blockIdx.y;
  const float4* s = (const float4*)a.src[seg];
  ushort4* d = (ushort4*)a.dst[seg];
  int n4 = a.n4[seg];
  for (int i = blockIdx.x*blockDim.x + threadIdx.x; i < n4; i += gridDim.x*blockDim.x){
    float4 v = s[i];
    ushort4 o;
    o.x = f2bf(v.x); o.y = f2bf(v.y); o.z = f2bf(v.z); o.w = f2bf(v.w);
    d[i] = o;
  }
}

// ---------------- GEMM: C(8192x512) = A(8192x512) @ W^T(512x512) + bias ----------------
// mode 0: dst_bf = head-major bf16 [B][H][L][64]   (Q/K projection)
// mode 1: dst_bf = transposed bf16 [B][H][64][L]   (V projection)
// mode 2: dst_f32 = plain fp32 [8192][512]         (output projection)
__global__ __launch_bounds__(256,4) void gemm512(
    const u16* __restrict__ A, const u16* __restrict__ W,
    const float* __restrict__ bias,
    u16* __restrict__ dst_bf, float* __restrict__ dst_f32, int mode)
{
  __shared__ u16 As[64*64];
  __shared__ u16 Bs[64*64];
  const int tid = threadIdx.x;
  const int w = tid>>6, lane = tid&63;
  const int g = lane>>4, r16 = lane&15;
  const int wr = w>>1, wc = w&1;
  const int m0 = blockIdx.x*64, n0 = blockIdx.y*64;

  f32x4 acc[2][2] = {};

  int rowc[2], slotc[2];
  #pragma unroll
  for (int i=0;i<2;++i){ int c = (i<<8)+tid; rowc[i]=c>>3; slotc[i]=c&7; }

  uint4 ra[2], rb[2];
  #pragma unroll
  for (int i=0;i<2;++i){
    ra[i] = *(const uint4*)(A + (size_t)(m0+rowc[i])*DM + slotc[i]*8);
    rb[i] = *(const uint4*)(W + (size_t)(n0+rowc[i])*DM + slotc[i]*8);
  }

  const int fswz = r16 & 7;

  for (int k0=0; k0<DM; k0+=64){
    __syncthreads();
    #pragma unroll
    for (int i=0;i<2;++i){
      *(uint4*)(&As[rowc[i]*64 + (slotc[i]^(rowc[i]&7))*8]) = ra[i];
      *(uint4*)(&Bs[rowc[i]*64 + (slotc[i]^(rowc[i]&7))*8]) = rb[i];
    }
    __syncthreads();
    int kn = (k0+64 < DM) ? (k0+64) : 0;
    #pragma unroll
    for (int i=0;i<2;++i){
      ra[i] = *(const uint4*)(A + (size_t)(m0+rowc[i])*DM + kn + slotc[i]*8);
      rb[i] = *(const uint4*)(W + (size_t)(n0+rowc[i])*DM + kn + slotc[i]*8);
    }
    bf16x8 af[2][2], bfr[2][2];
    #pragma unroll
    for (int mi=0; mi<2; ++mi){
      int row = wr*32 + mi*16 + r16;
      #pragma unroll
      for (int ks=0; ks<2; ++ks)
        af[mi][ks] = *(const bf16x8*)(&As[row*64 + ((ks*4+g)^fswz)*8]);
    }
    #pragma unroll
    for (int ni=0; ni<2; ++ni){
      int row = wc*32 + ni*16 + r16;
      #pragma unroll
      for (int ks=0; ks<2; ++ks)
        bfr[ni][ks] = *(const bf16x8*)(&Bs[row*64 + ((ks*4+g)^fswz)*8]);
    }
    #pragma unroll
    for (int mi=0; mi<2; ++mi)
      #pragma unroll
      for (int ni=0; ni<2; ++ni){
        acc[mi][ni] = mfma16(af[mi][0], bfr[ni][0], acc[mi][ni]);
        acc[mi][ni] = mfma16(af[mi][1], bfr[ni][1], acc[mi][ni]);
      }
  }

  #pragma unroll
  for (int mi=0; mi<2; ++mi){
    #pragma unroll
    for (int ni=0; ni<2; ++ni){
      int mrow0 = m0 + wr*32 + mi*16 + g*4;
      int ncol = n0 + wc*32 + ni*16 + r16;
      float bv = bias[ncol];
      if (mode == 0){
        int h = ncol>>6, d = ncol&63;
        #pragma unroll
        for (int r=0;r<4;++r){
          int m = mrow0 + r;
          int b = m>>10, ls = m&1023;
          dst_bf[(size_t)((b*HH+h)*LL + ls)*DH + d] = f2bf(acc[mi][ni][r] + bv);
        }
      } else if (mode == 1){
        int h = ncol>>6, d = ncol&63;
        int b = mrow0>>10, ls = mrow0&1023;
        ushort4 o;
        o.x = f2bf(acc[mi][ni][0] + bv);
        o.y = f2bf(acc[mi][ni][1] + bv);
        o.z = f2bf(acc[mi][ni][2] + bv);
        o.w = f2bf(acc[mi][ni][3] + bv);
        *(ushort4*)(dst_bf + (size_t)((b*HH+h)*DH + d)*LL + ls) = o;
      } else {
        #pragma unroll
        for (int r=0;r<4;++r){
          int m = mrow0 + r;
          dst_f32[(size_t)m*DM + ncol] = acc[mi][ni][r] + bv;
        }
      }
    }
  }
}

// ---------------- fused attention + entmax-1.5 ----------------
// grid (32, 64): x = q-block of 32 rows, y = b*8+h. 512 threads (8 waves).
// LDS: S [32][1024] fp32 row-swizzled; reused as P [32][1024] bf16 row-swizzled.
__global__ __launch_bounds__(512,2) void attn_entmax(
    const u16* __restrict__ Qp, const u16* __restrict__ Kp,
    const u16* __restrict__ Vt, const unsigned char* __restrict__ mask,
    u16* __restrict__ ctx)
{
  extern __shared__ char smem[];
  float* S = (float*)smem;
  u16*  P = (u16*)smem;

  const int tid = threadIdx.x;
  const int w = tid>>6, lane = tid&63;
  const int g = lane>>4, r16 = lane&15;
  const int bh = blockIdx.y;
  const int b = bh>>3, h = bh&7;
  const int q0 = blockIdx.x*32;

  const u16* Qb = Qp + (size_t)bh*LL*DH;
  const u16* Kb = Kp + (size_t)bh*LL*DH;

  // ---- Phase A: S = (Q K^T) * scale / 2 ; wave w owns keys [w*128, w*128+128)
  bf16x8 qf[2][2];
  #pragma unroll
  for (int qi=0;qi<2;++qi)
    #pragma unroll
    for (int ks=0;ks<2;++ks)
      qf[qi][ks] = *(const bf16x8*)(Qb + (size_t)(q0+qi*16+r16)*DH + ks*32 + g*8);

  f32x4 acc[2][8] = {};
  #pragma unroll
  for (int kt=0;kt<8;++kt){
    int key = w*128 + kt*16 + r16;
    const u16* kp = Kb + (size_t)key*DH + g*8;
    bf16x8 kf0 = *(const bf16x8*)(kp);
    bf16x8 kf1 = *(const bf16x8*)(kp + 32);
    acc[0][kt] = mfma16(qf[0][0], kf0, acc[0][kt]);
    acc[0][kt] = mfma16(qf[0][1], kf1, acc[0][kt]);
    acc[1][kt] = mfma16(qf[1][0], kf0, acc[1][kt]);
    acc[1][kt] = mfma16(qf[1][1], kf1, acc[1][kt]);
  }
  #pragma unroll
  for (int kt=0;kt<8;++kt){
    int key = w*128 + kt*16 + r16;
    bool mk = mask[b*LL + key] != 0;
    #pragma unroll
    for (int qi=0;qi<2;++qi)
      #pragma unroll
      for (int r=0;r<4;++r){
        int row = qi*16 + g*4 + r;
        float sv = mk ? -5.0e8f : acc[qi][kt][r]*0.0625f; // *(1/8 scale)*(1/2)
        S[row*1024 + (key ^ ((row&7)<<2))] = sv;
      }
  }
  __syncthreads();

  // ---- Phase B: entmax-1.5 via safeguarded Newton; wave w owns rows w*4..w*4+3
  u32 pp[4][8];
  #pragma unroll
  for (int rr=0; rr<4; ++rr){
    int r = w*4 + rr;
    int sw = (r&7)<<2;
    float z[16];
    #pragma unroll
    for (int e=0;e<16;++e)
      z[e] = S[r*1024 + ((e*64 + lane) ^ sw)];
    float mx = z[0];
    #pragma unroll
    for (int e=1;e<16;++e) mx = fmaxf(mx, z[e]);
    #pragma unroll
    for (int off=32; off>=1; off>>=1) mx = fmaxf(mx, __shfl_xor(mx, off));
    #pragma unroll
    for (int e=0;e<16;++e) z[e] -= mx;

    float lo = -1.0f, hi = 0.0f, tau = -1.0f;
    #pragma unroll 1
    for (int it=0; it<12; ++it){
      float s1 = 0.f, s2 = 0.f;
      #pragma unroll
      for (int e=0;e<16;++e){
        float dd = fmaxf(z[e]-tau, 0.f);
        s1 += dd; s2 = fmaf(dd, dd, s2);
      }
      #pragma unroll
      for (int off=32; off>=1; off>>=1){
        s1 += __shfl_xor(s1, off);
        s2 += __shfl_xor(s2, off);
      }
      if (s2 >= 1.0f) lo = tau; else hi = tau;
      float t2 = tau + (s2 - 1.0f)/(2.0f*s1);
      tau = (t2 >= lo && t2 < hi) ? t2 : 0.5f*(lo+hi);
    }
    float p[16]; float ps = 0.f;
    #pragma unroll
    for (int e=0;e<16;++e){
      float dd = fmaxf(z[e]-tau, 0.f);
      p[e] = dd*dd; ps += p[e];
    }
    #pragma unroll
    for (int off=32; off>=1; off>>=1) ps += __shfl_xor(ps, off);
    float inv = 1.0f/ps;
    #pragma unroll
    for (int e=0;e<8;++e)
      pp[rr][e] = (u32)f2bf(p[2*e]*inv) | ((u32)f2bf(p[2*e+1]*inv) << 16);
  }
  __syncthreads();

  // write P (bf16, swizzled) — safe now: all S reads complete
  #pragma unroll
  for (int rr=0; rr<4; ++rr){
    int r = w*4 + rr;
    int sw = (r&7)<<3;
    #pragma unroll
    for (int e=0;e<16;++e){
      u16 v = (e&1) ? (u16)(pp[rr][e>>1]>>16) : (u16)(pp[rr][e>>1]&0xFFFFu);
      P[r*1024 + ((e*64 + lane) ^ sw)] = v;
    }
  }
  __syncthreads();

  // ---- Phase C: ctx = P @ V ; wave w -> q-tile (w>>2), d-tile (w&3)
  const int qi = w>>2, di = w&3;
  const u16* Vb = Vt + (size_t)bh*DH*LL;
  f32x4 oacc = {};
  const int prow = qi*16 + r16;
  const int psw = (prow&7)<<3;
  const u16* vrow = Vb + (size_t)(di*16 + r16)*LL;
  #pragma unroll 4
  for (int kt=0; kt<32; ++kt){
    bf16x8 pa = *(const bf16x8*)(&P[prow*1024 + ((kt*32 + g*8) ^ psw)]);
    bf16x8 vb = *(const bf16x8*)(vrow + kt*32 + g*8);
    oacc = mfma16(pa, vb, oacc);
  }
  #pragma unroll
  for (int r=0;r<4;++r){
    int q = q0 + qi*16 + g*4 + r;
    ctx[(size_t)(b*LL + q)*DM + h*DH + di*16 + r16] = f2bf(oacc[r]);
  }
}

// ---------------- launch ----------------
extern "C" void kernel_launch(void* const* d_in, const int* in_sizes, int n_in,
                              void* d_out, int out_size, void* d_ws, size_t ws_size,
                              hipStream_t stream) {
  const float* query = (const float*)d_in[0];
  const float* key   = (const float*)d_in[1];
  const float* value = (const float*)d_in[2];
  const unsigned char* maskp = (const unsigned char*)d_in[3];
  const float* q_w = (const float*)d_in[4];
  const float* q_b = (const float*)d_in[5];
  const float* k_w = (const float*)d_in[6];
  const float* k_b = (const float*)d_in[7];
  const float* v_w = (const float*)d_in[8];
  const float* v_b = (const float*)d_in[9];
  const float* out_w = (const float*)d_in[10];
  const float* out_b = (const float*)d_in[11];
  float* out = (float*)d_out;

  u16* qx = (u16*)d_ws;                 // 4M elems each
  u16* kx = qx + 4194304;
  u16* vx = kx + 4194304;
  u16* wq = vx + 4194304;               // 256K elems each
  u16* wk = wq + 262144;
  u16* wv = wk + 262144;
  u16* wo = wv + 262144;
  u16* Qp = wo + 262144;                // 4M elems each
  u16* Kp = Qp + 4194304;
  u16* Vt = Kp + 4194304;
  u16* ctx = Vt + 4194304;

  CvtArgs ca;
  ca.src[0]=query; ca.dst[0]=qx; ca.n4[0]=BB*LL*DM/4;
  ca.src[1]=key;   ca.dst[1]=kx; ca.n4[1]=BB*LL*DM/4;
  ca.src[2]=value; ca.dst[2]=vx; ca.n4[2]=BB*LL*DM/4;
  ca.src[3]=q_w;   ca.dst[3]=wq; ca.n4[3]=DM*DM/4;
  ca.src[4]=k_w;   ca.dst[4]=wk; ca.n4[4]=DM*DM/4;
  ca.src[5]=v_w;   ca.dst[5]=wv; ca.n4[5]=DM*DM/4;
  ca.src[6]=out_w; ca.dst[6]=wo; ca.n4[6]=DM*DM/4;
  cvt_kernel<<<dim3(512,7),256,0,stream>>>(ca);

  gemm512<<<dim3(128,8),256,0,stream>>>(qx, wq, q_b, Qp, nullptr, 0);
  gemm512<<<dim3(128,8),256,0,stream>>>(kx, wk, k_b, Kp, nullptr, 0);
  gemm512<<<dim3(128,8),256,0,stream>>>(vx, wv, v_b, Vt, nullptr, 1);

  hipFuncSetAttribute((const void*)attn_entmax,
                      hipFuncAttributeMaxDynamicSharedMemorySize, 131072);
  attn_entmax<<<dim3(32,64),512,131072,stream>>>(Qp, Kp, Vt, maskp, ctx);

  gemm512<<<dim3(128,8),256,0,stream>>>(ctx, wo, out_b, nullptr, out, 2);
}

// Round 2
// 310.900 us; speedup vs baseline: 1.6010x; 1.6010x over previous
//
#include <hip/hip_runtime.h>
#include <hip/hip_bf16.h>
#include <stdint.h>

typedef __attribute__((ext_vector_type(8))) short bf16x8;
typedef __attribute__((ext_vector_type(4))) float f32x4;
typedef unsigned short u16;
typedef unsigned int u32;

#define BB 8
#define HH 8
#define LL 1024
#define DM 512
#define DH 64

__device__ __forceinline__ u16 f2bf(float f){
  u32 u = __builtin_bit_cast(u32, f);
  u32 r = u + 0x7FFFu + ((u>>16)&1u);   // RNE
  return (u16)(r>>16);
}
__device__ __forceinline__ u16 f2h(float f){
  return __builtin_bit_cast(u16, (_Float16)f);
}
__device__ __forceinline__ float h2f(u16 h){
  return (float)__builtin_bit_cast(_Float16, h);
}

__device__ __forceinline__ f32x4 mfma16(bf16x8 a, bf16x8 b, f32x4 c){
  return __builtin_amdgcn_mfma_f32_16x16x32_bf16(a, b, c, 0, 0, 0);
}

// ---------------- fp32 -> bf16 convert ----------------
struct CvtArgs {
  const float* src[7];
  u16* dst[7];
  int n4[7];
};

__global__ __launch_bounds__(256) void cvt_kernel(CvtArgs a){
  int seg = blockIdx.y;
  const float4* s = (const float4*)a.src[seg];
  ushort4* d = (ushort4*)a.dst[seg];
  int n4 = a.n4[seg];
  for (int i = blockIdx.x*blockDim.x + threadIdx.x; i < n4; i += gridDim.x*blockDim.x){
    float4 v = s[i];
    ushort4 o;
    o.x = f2bf(v.x); o.y = f2bf(v.y); o.z = f2bf(v.z); o.w = f2bf(v.w);
    d[i] = o;
  }
}

// ---------------- GEMM: C(8192x512) = A(8192x512) @ W^T(512x512) + bias ----------------
// mode 0: dst_bf = head-major bf16 [B][H][L][64]   (Q/K projection)
// mode 1: dst_bf = transposed bf16 [B][H][64][L]   (V projection)
// mode 2: dst_f32 = plain fp32 [8192][512]         (output projection)
__global__ __launch_bounds__(256,4) void gemm512(
    const u16* __restrict__ A, const u16* __restrict__ W,
    const float* __restrict__ bias,
    u16* __restrict__ dst_bf, float* __restrict__ dst_f32, int mode)
{
  __shared__ u16 As[64*64];
  __shared__ u16 Bs[64*64];
  const int tid = threadIdx.x;
  const int w = tid>>6, lane = tid&63;
  const int g = lane>>4, r16 = lane&15;
  const int wr = w>>1, wc = w&1;
  const int m0 = blockIdx.x*64, n0 = blockIdx.y*64;

  f32x4 acc[2][2] = {};

  int rowc[2], slotc[2];
  #pragma unroll
  for (int i=0;i<2;++i){ int c = (i<<8)+tid; rowc[i]=c>>3; slotc[i]=c&7; }

  uint4 ra[2], rb[2];
  #pragma unroll
  for (int i=0;i<2;++i){
    ra[i] = *(const uint4*)(A + (size_t)(m0+rowc[i])*DM + slotc[i]*8);
    rb[i] = *(const uint4*)(W + (size_t)(n0+rowc[i])*DM + slotc[i]*8);
  }

  const int fswz = r16 & 7;

  for (int k0=0; k0<DM; k0+=64){
    __syncthreads();
    #pragma unroll
    for (int i=0;i<2;++i){
      *(uint4*)(&As[rowc[i]*64 + (slotc[i]^(rowc[i]&7))*8]) = ra[i];
      *(uint4*)(&Bs[rowc[i]*64 + (slotc[i]^(rowc[i]&7))*8]) = rb[i];
    }
    __syncthreads();
    int kn = (k0+64 < DM) ? (k0+64) : 0;
    #pragma unroll
    for (int i=0;i<2;++i){
      ra[i] = *(const uint4*)(A + (size_t)(m0+rowc[i])*DM + kn + slotc[i]*8);
      rb[i] = *(const uint4*)(W + (size_t)(n0+rowc[i])*DM + kn + slotc[i]*8);
    }
    bf16x8 af[2][2], bfr[2][2];
    #pragma unroll
    for (int mi=0; mi<2; ++mi){
      int row = wr*32 + mi*16 + r16;
      #pragma unroll
      for (int ks=0; ks<2; ++ks)
        af[mi][ks] = *(const bf16x8*)(&As[row*64 + ((ks*4+g)^fswz)*8]);
    }
    #pragma unroll
    for (int ni=0; ni<2; ++ni){
      int row = wc*32 + ni*16 + r16;
      #pragma unroll
      for (int ks=0; ks<2; ++ks)
        bfr[ni][ks] = *(const bf16x8*)(&Bs[row*64 + ((ks*4+g)^fswz)*8]);
    }
    #pragma unroll
    for (int mi=0; mi<2; ++mi)
      #pragma unroll
      for (int ni=0; ni<2; ++ni){
        acc[mi][ni] = mfma16(af[mi][0], bfr[ni][0], acc[mi][ni]);
        acc[mi][ni] = mfma16(af[mi][1], bfr[ni][1], acc[mi][ni]);
      }
  }

  #pragma unroll
  for (int mi=0; mi<2; ++mi){
    #pragma unroll
    for (int ni=0; ni<2; ++ni){
      int mrow0 = m0 + wr*32 + mi*16 + g*4;
      int ncol = n0 + wc*32 + ni*16 + r16;
      float bv = bias[ncol];
      if (mode == 0){
        int h = ncol>>6, d = ncol&63;
        #pragma unroll
        for (int r=0;r<4;++r){
          int m = mrow0 + r;
          int b = m>>10, ls = m&1023;
          dst_bf[(size_t)((b*HH+h)*LL + ls)*DH + d] = f2bf(acc[mi][ni][r] + bv);
        }
      } else if (mode == 1){
        int h = ncol>>6, d = ncol&63;
        int b = mrow0>>10, ls = mrow0&1023;
        ushort4 o;
        o.x = f2bf(acc[mi][ni][0] + bv);
        o.y = f2bf(acc[mi][ni][1] + bv);
        o.z = f2bf(acc[mi][ni][2] + bv);
        o.w = f2bf(acc[mi][ni][3] + bv);
        *(ushort4*)(dst_bf + (size_t)((b*HH+h)*DH + d)*LL + ls) = o;
      } else {
        #pragma unroll
        for (int r=0;r<4;++r){
          int m = mrow0 + r;
          dst_f32[(size_t)m*DM + ncol] = acc[mi][ni][r] + bv;
        }
      }
    }
  }
}

// ---------------- fused attention + entmax-1.5 ----------------
// grid (32, 64): x = q-block of 32 rows, y = b*8+h. 512 threads (8 waves).
// One shared 64 KiB u16 buffer [32][1024]: f16 scores S, then bf16 probs P.
// Swizzle: element (row,k) lives at u16 offset row*1024 + (k ^ (cc<<3)),
//   cc = ((k>>6)&7) ^ (row&7).   (bijective: XOR mask depends only on bits>=6)
__global__ __launch_bounds__(512,4) void attn_entmax(
    const u16* __restrict__ Qp, const u16* __restrict__ Kp,
    const u16* __restrict__ Vt, const unsigned char* __restrict__ mask,
    u16* __restrict__ ctx)
{
  __shared__ u16 S[32*1024];   // 64 KiB -> 2 blocks/CU

  const int tid = threadIdx.x;
  const int w = tid>>6, lane = tid&63;
  const int g = lane>>4, r16 = lane&15;
  const int bh = blockIdx.y;
  const int b = bh>>3, h = bh&7;
  const int q0 = blockIdx.x*32;

  const u16* Qb = Qp + (size_t)bh*LL*DH;
  const u16* Kb = Kp + (size_t)bh*LL*DH;

  // ---- Phase A: S = (Q K^T) * scale / 2 ; wave w owns keys [w*128, w*128+128)
  bf16x8 qf[2][2];
  #pragma unroll
  for (int qi=0;qi<2;++qi)
    #pragma unroll
    for (int ks=0;ks<2;++ks)
      qf[qi][ks] = *(const bf16x8*)(Qb + (size_t)(q0+qi*16+r16)*DH + ks*32 + g*8);

  f32x4 acc[2][8] = {};
  #pragma unroll
  for (int kt=0;kt<8;++kt){
    int key = w*128 + kt*16 + r16;
    const u16* kp = Kb + (size_t)key*DH + g*8;
    bf16x8 kf0 = *(const bf16x8*)(kp);
    bf16x8 kf1 = *(const bf16x8*)(kp + 32);
    acc[0][kt] = mfma16(qf[0][0], kf0, acc[0][kt]);
    acc[0][kt] = mfma16(qf[0][1], kf1, acc[0][kt]);
    acc[1][kt] = mfma16(qf[1][0], kf0, acc[1][kt]);
    acc[1][kt] = mfma16(qf[1][1], kf1, acc[1][kt]);
  }
  #pragma unroll
  for (int kt=0;kt<8;++kt){
    int key = w*128 + kt*16 + r16;
    bool mk = mask[b*LL + key] != 0;
    #pragma unroll
    for (int qi=0;qi<2;++qi)
      #pragma unroll
      for (int r=0;r<4;++r){
        int row = qi*16 + g*4 + r;
        float sv = mk ? -30000.0f : acc[qi][kt][r]*0.0625f; // *(1/8)*(1/2)
        int cc = ((key>>6)&7) ^ (row&7);
        S[row*1024 + (key ^ (cc<<3))] = f2h(sv);
      }
  }
  __syncthreads();

  // ---- Phase B: entmax-1.5, one row per 16-lane group (4 rows/wave in parallel)
  // lane holds 64 contiguous keys [r16*64, r16*64+64) of row r = w*4+g.
  {
    const int r = w*4 + g;
    const int ccb = (r16 ^ r) & 7;
    float z[64];
    #pragma unroll
    for (int c=0;c<8;++c){
      uint4 v = *(const uint4*)(&S[r*1024 + ((r16*64 + c*8) ^ (ccb<<3))]);
      const u16* hp = (const u16*)&v;
      #pragma unroll
      for (int t=0;t<8;++t) z[c*8+t] = h2f(hp[t]);
    }
    // row max (4 shuffle levels within the 16-lane group)
    float mx = z[0];
    #pragma unroll
    for (int e=1;e<64;++e) mx = fmaxf(mx, z[e]);
    #pragma unroll
    for (int off=8; off>=1; off>>=1) mx = fmaxf(mx, __shfl_xor(mx, off));
    #pragma unroll
    for (int e=0;e<64;++e) z[e] -= mx;

    // safeguarded Newton on f(tau) = sum max(z-tau,0)^2 - 1, root in [-1,0]
    float lo = -1.0f, hi = 0.0f, tau = -0.5f;
    #pragma unroll 1
    for (int it=0; it<10; ++it){
      float s1a=0.f,s1b=0.f,s2a=0.f,s2b=0.f;
      #pragma unroll
      for (int e=0;e<64;e+=2){
        float d0 = fmaxf(z[e]-tau, 0.f);
        float d1 = fmaxf(z[e+1]-tau, 0.f);
        s1a += d0; s2a = fmaf(d0,d0,s2a);
        s1b += d1; s2b = fmaf(d1,d1,s2b);
      }
      float s1 = s1a+s1b, s2 = s2a+s2b;
      #pragma unroll
      for (int off=8; off>=1; off>>=1){
        s1 += __shfl_xor(s1, off);
        s2 += __shfl_xor(s2, off);
      }
      if (s2 >= 1.0f) lo = tau; else hi = tau;
      float t2 = tau + (s2 - 1.0f)/(2.0f*s1);
      tau = (t2 >= lo && t2 < hi) ? t2 : 0.5f*(lo+hi);
    }

    // p = (z-tau)_+^2, renormalize, pack bf16, write back to same slots
    float psa=0.f, psb=0.f;
    #pragma unroll
    for (int e=0;e<64;e+=2){
      float d0 = fmaxf(z[e]-tau, 0.f);
      float d1 = fmaxf(z[e+1]-tau, 0.f);
      z[e] = d0*d0;  psa += z[e];
      z[e+1] = d1*d1; psb += z[e+1];
    }
    float ps = psa+psb;
    #pragma unroll
    for (int off=8; off>=1; off>>=1) ps += __shfl_xor(ps, off);
    float inv = 1.0f/ps;
    #pragma unroll
    for (int c=0;c<8;++c){
      u32 o0 = (u32)f2bf(z[c*8+0]*inv) | ((u32)f2bf(z[c*8+1]*inv)<<16);
      u32 o1 = (u32)f2bf(z[c*8+2]*inv) | ((u32)f2bf(z[c*8+3]*inv)<<16);
      u32 o2 = (u32)f2bf(z[c*8+4]*inv) | ((u32)f2bf(z[c*8+5]*inv)<<16);
      u32 o3 = (u32)f2bf(z[c*8+6]*inv) | ((u32)f2bf(z[c*8+7]*inv)<<16);
      uint4 vv; vv.x=o0; vv.y=o1; vv.z=o2; vv.w=o3;
      // same slots this lane read -> no cross-lane hazard, no barrier needed here
      *(uint4*)(&S[r*1024 + ((r16*64 + c*8) ^ (ccb<<3))]) = vv;
    }
  }
  __syncthreads();

  // ---- Phase C: ctx = P @ V ; wave w -> q-tile (w>>2), d-tile (w&3)
  const int qi = w>>2, di = w&3;
  const u16* vrow = Vt + (size_t)bh*DH*LL + (size_t)(di*16 + r16)*LL;
  f32x4 o0 = {}, o1 = {};
  const int prow = qi*16 + r16;
  #pragma unroll 8
  for (int kt=0; kt<32; ++kt){
    int k = kt*32 + g*8;
    int ccc = ((k>>6)&7) ^ (prow&7);
    bf16x8 pa = *(const bf16x8*)(&S[prow*1024 + (k ^ (ccc<<3))]);
    bf16x8 vb = *(const bf16x8*)(vrow + k);
    if (kt & 1) o1 = mfma16(pa, vb, o1);
    else        o0 = mfma16(pa, vb, o0);
  }
  #pragma unroll
  for (int r=0;r<4;++r){
    int q = q0 + qi*16 + g*4 + r;
    ctx[(size_t)(b*LL + q)*DM + h*DH + di*16 + r16] = f2bf(o0[r] + o1[r]);
  }
}

// ---------------- launch ----------------
extern "C" void kernel_launch(void* const* d_in, const int* in_sizes, int n_in,
                              void* d_out, int out_size, void* d_ws, size_t ws_size,
                              hipStream_t stream) {
  const float* query = (const float*)d_in[0];
  const float* key   = (const float*)d_in[1];
  const float* value = (const float*)d_in[2];
  const unsigned char* maskp = (const unsigned char*)d_in[3];
  const float* q_w = (const float*)d_in[4];
  const float* q_b = (const float*)d_in[5];
  const float* k_w = (const float*)d_in[6];
  const float* k_b = (const float*)d_in[7];
  const float* v_w = (const float*)d_in[8];
  const float* v_b = (const float*)d_in[9];
  const float* out_w = (const float*)d_in[10];
  const float* out_b = (const float*)d_in[11];
  float* out = (float*)d_out;

  u16* qx = (u16*)d_ws;                 // 4M elems each
  u16* kx = qx + 4194304;
  u16* vx = kx + 4194304;
  u16* wq = vx + 4194304;               // 256K elems each
  u16* wk = wq + 262144;
  u16* wv = wk + 262144;
  u16* wo = wv + 262144;
  u16* Qp = wo + 262144;                // 4M elems each
  u16* Kp = Qp + 4194304;
  u16* Vt = Kp + 4194304;
  u16* ctx = Vt + 4194304;

  CvtArgs ca;
  ca.src[0]=query; ca.dst[0]=qx; ca.n4[0]=BB*LL*DM/4;
  ca.src[1]=key;   ca.dst[1]=kx; ca.n4[1]=BB*LL*DM/4;
  ca.src[2]=value; ca.dst[2]=vx; ca.n4[2]=BB*LL*DM/4;
  ca.src[3]=q_w;   ca.dst[3]=wq; ca.n4[3]=DM*DM/4;
  ca.src[4]=k_w;   ca.dst[4]=wk; ca.n4[4]=DM*DM/4;
  ca.src[5]=v_w;   ca.dst[5]=wv; ca.n4[5]=DM*DM/4;
  ca.src[6]=out_w; ca.dst[6]=wo; ca.n4[6]=DM*DM/4;
  cvt_kernel<<<dim3(512,7),256,0,stream>>>(ca);

  gemm512<<<dim3(128,8),256,0,stream>>>(qx, wq, q_b, Qp, nullptr, 0);
  gemm512<<<dim3(128,8),256,0,stream>>>(kx, wk, k_b, Kp, nullptr, 0);
  gemm512<<<dim3(128,8),256,0,stream>>>(vx, wv, v_b, Vt, nullptr, 1);

  attn_entmax<<<dim3(32,64),512,0,stream>>>(Qp, Kp, Vt, maskp, ctx);

  gemm512<<<dim3(128,8),256,0,stream>>>(ctx, wo, out_b, nullptr, out, 2);
}

// Round 3
// 252.948 us; speedup vs baseline: 1.9678x; 1.2291x over previous
//
#include <hip/hip_runtime.h>
#include <stdint.h>

typedef _Float16 f16;
typedef __attribute__((ext_vector_type(8))) f16 f16x8;
typedef __attribute__((ext_vector_type(2))) f16 h2;
typedef __attribute__((ext_vector_type(4))) float f32x4;
typedef unsigned short u16;
typedef unsigned int u32;

#define BB 8
#define HH 8
#define LL 1024
#define DM 512
#define DH 64

__device__ __forceinline__ u16 f2h(float f){
  return __builtin_bit_cast(u16, (f16)f);
}

__device__ __forceinline__ f32x4 mfma16h(f16x8 a, f16x8 b, f32x4 c){
  return __builtin_amdgcn_mfma_f32_16x16x32_f16(a, b, c, 0, 0, 0);
}

// ---------------- fp32 -> f16 convert ----------------
struct CvtArgs {
  const float* src[7];
  u16* dst[7];
  int n4[7];
};

__global__ __launch_bounds__(256) void cvt_kernel(CvtArgs a){
  int seg = blockIdx.y;
  const float4* s = (const float4*)a.src[seg];
  ushort4* d = (ushort4*)a.dst[seg];
  int n4 = a.n4[seg];
  for (int i = blockIdx.x*blockDim.x + threadIdx.x; i < n4; i += gridDim.x*blockDim.x){
    float4 v = s[i];
    ushort4 o;
    o.x = f2h(v.x); o.y = f2h(v.y); o.z = f2h(v.z); o.w = f2h(v.w);
    d[i] = o;
  }
}

// ---------------- GEMM 128x128 tile: C(8192x512) = A(8192x512) @ W^T + bias ----------------
// mode 0: dst_h = head-major f16 [B][H][L][64]   (Q/K projection; scale folds 1/16 for Q)
// mode 1: dst_h = transposed f16 [B][H][64][L]   (V projection)
// mode 2: dst_f32 = plain fp32 [8192][512]       (output projection)
__global__ __launch_bounds__(256,2) void gemm128(
    const u16* __restrict__ A, const u16* __restrict__ W,
    const float* __restrict__ bias,
    u16* __restrict__ dst_h, float* __restrict__ dst_f32, int mode, float scale)
{
  __shared__ u16 As[128*64];
  __shared__ u16 Bs[128*64];
  const int tid = threadIdx.x;
  const int w = tid>>6, lane = tid&63;
  const int g = lane>>4, r16 = lane&15;
  const int wr = w>>1, wc = w&1;
  const int m0 = blockIdx.x*128, n0 = blockIdx.y*128;

  f32x4 acc[4][4] = {};

  int rowc[4], slotc[4];
  #pragma unroll
  for (int i=0;i<4;++i){ int c = i*256+tid; rowc[i]=c>>3; slotc[i]=c&7; }

  uint4 ra[4], rb[4];
  #pragma unroll
  for (int i=0;i<4;++i){
    ra[i] = *(const uint4*)(A + (size_t)(m0+rowc[i])*DM + slotc[i]*8);
    rb[i] = *(const uint4*)(W + (size_t)(n0+rowc[i])*DM + slotc[i]*8);
  }

  const int fswz = r16 & 7;

  for (int k0=0; k0<DM; k0+=64){
    __syncthreads();
    #pragma unroll
    for (int i=0;i<4;++i){
      *(uint4*)(&As[rowc[i]*64 + (slotc[i]^(rowc[i]&7))*8]) = ra[i];
      *(uint4*)(&Bs[rowc[i]*64 + (slotc[i]^(rowc[i]&7))*8]) = rb[i];
    }
    __syncthreads();
    int kn = (k0+64 < DM) ? (k0+64) : 0;
    #pragma unroll
    for (int i=0;i<4;++i){
      ra[i] = *(const uint4*)(A + (size_t)(m0+rowc[i])*DM + kn + slotc[i]*8);
      rb[i] = *(const uint4*)(W + (size_t)(n0+rowc[i])*DM + kn + slotc[i]*8);
    }
    f16x8 af[4][2], bfr[4][2];
    #pragma unroll
    for (int mi=0; mi<4; ++mi){
      int row = wr*64 + mi*16 + r16;
      #pragma unroll
      for (int ks=0; ks<2; ++ks)
        af[mi][ks] = *(const f16x8*)(&As[row*64 + ((ks*4+g)^fswz)*8]);
    }
    #pragma unroll
    for (int ni=0; ni<4; ++ni){
      int row = wc*64 + ni*16 + r16;
      #pragma unroll
      for (int ks=0; ks<2; ++ks)
        bfr[ni][ks] = *(const f16x8*)(&Bs[row*64 + ((ks*4+g)^fswz)*8]);
    }
    #pragma unroll
    for (int mi=0; mi<4; ++mi)
      #pragma unroll
      for (int ni=0; ni<4; ++ni){
        acc[mi][ni] = mfma16h(af[mi][0], bfr[ni][0], acc[mi][ni]);
        acc[mi][ni] = mfma16h(af[mi][1], bfr[ni][1], acc[mi][ni]);
      }
  }

  #pragma unroll
  for (int mi=0; mi<4; ++mi){
    #pragma unroll
    for (int ni=0; ni<4; ++ni){
      int mrow0 = m0 + wr*64 + mi*16 + g*4;
      int ncol = n0 + wc*64 + ni*16 + r16;
      float bv = bias[ncol];
      if (mode == 0){
        int h = ncol>>6, d = ncol&63;
        #pragma unroll
        for (int r=0;r<4;++r){
          int m = mrow0 + r;
          int b = m>>10, ls = m&1023;
          dst_h[(size_t)((b*HH+h)*LL + ls)*DH + d] = f2h((acc[mi][ni][r] + bv)*scale);
        }
      } else if (mode == 1){
        int h = ncol>>6, d = ncol&63;
        int b = mrow0>>10, ls = mrow0&1023;
        ushort4 o;
        o.x = f2h(acc[mi][ni][0] + bv);
        o.y = f2h(acc[mi][ni][1] + bv);
        o.z = f2h(acc[mi][ni][2] + bv);
        o.w = f2h(acc[mi][ni][3] + bv);
        *(ushort4*)(dst_h + (size_t)((b*HH+h)*DH + d)*LL + ls) = o;
      } else {
        #pragma unroll
        for (int r=0;r<4;++r){
          int m = mrow0 + r;
          dst_f32[(size_t)m*DM + ncol] = acc[mi][ni][r] + bv;
        }
      }
    }
  }
}

// ---------------- fused attention + entmax-1.5 ----------------
// grid (32, 64): x = q-block of 32 rows, y = b*8+h. 512 threads (8 waves).
// One shared 64 KiB u16 buffer [32][1024]: f16 scores S, then f16 probs P.
// Swizzle: element (row,k) lives at u16 offset row*1024 + (k ^ (cc<<3)),
//   cc = ((k>>6)&7) ^ (row&7).
__global__ __launch_bounds__(512,4) void attn_entmax(
    const u16* __restrict__ Qp, const u16* __restrict__ Kp,
    const u16* __restrict__ Vt, const unsigned char* __restrict__ mask,
    u16* __restrict__ ctx)
{
  __shared__ u16 S[32*1024];   // 64 KiB -> 2 blocks/CU

  const int tid = threadIdx.x;
  const int w = tid>>6, lane = tid&63;
  const int g = lane>>4, r16 = lane&15;
  const int bh = blockIdx.y;
  const int b = bh>>3, h = bh&7;
  const int q0 = blockIdx.x*32;

  const u16* Qb = Qp + (size_t)bh*LL*DH;
  const u16* Kb = Kp + (size_t)bh*LL*DH;

  // ---- Phase A: S = Q K^T (scale pre-folded into Q); wave w owns keys [w*128, w*128+128)
  f16x8 qf[2][2];
  #pragma unroll
  for (int qi=0;qi<2;++qi)
    #pragma unroll
    for (int ks=0;ks<2;++ks)
      qf[qi][ks] = *(const f16x8*)(Qb + (size_t)(q0+qi*16+r16)*DH + ks*32 + g*8);

  f32x4 acc[2][8] = {};
  #pragma unroll
  for (int kt=0;kt<8;++kt){
    int key = w*128 + kt*16 + r16;
    const u16* kp = Kb + (size_t)key*DH + g*8;
    f16x8 kf0 = *(const f16x8*)(kp);
    f16x8 kf1 = *(const f16x8*)(kp + 32);
    acc[0][kt] = mfma16h(qf[0][0], kf0, acc[0][kt]);
    acc[0][kt] = mfma16h(qf[0][1], kf1, acc[0][kt]);
    acc[1][kt] = mfma16h(qf[1][0], kf0, acc[1][kt]);
    acc[1][kt] = mfma16h(qf[1][1], kf1, acc[1][kt]);
  }
  #pragma unroll
  for (int kt=0;kt<8;++kt){
    int key = w*128 + kt*16 + r16;
    bool mk = mask[b*LL + key] != 0;
    #pragma unroll
    for (int qi=0;qi<2;++qi)
      #pragma unroll
      for (int r=0;r<4;++r){
        int row = qi*16 + g*4 + r;
        float sv = mk ? -30000.0f : acc[qi][kt][r];
        int cc = ((key>>6)&7) ^ (row&7);
        S[row*1024 + (key ^ (cc<<3))] = f2h(sv);
      }
  }
  __syncthreads();

  // ---- Phase B: entmax-1.5, one row per 16-lane group, packed-f16 Newton.
  // lane holds 64 contiguous keys [r16*64, r16*64+64) of row r = w*4+g as 32 f16x2.
  {
    const int r = w*4 + g;
    const int ccb = (r16 ^ r) & 7;
    h2 zp[32];
    #pragma unroll
    for (int c=0;c<8;++c){
      uint4 v = *(const uint4*)(&S[r*1024 + ((r16*64 + c*8) ^ (ccb<<3))]);
      zp[c*4+0] = __builtin_bit_cast(h2, v.x);
      zp[c*4+1] = __builtin_bit_cast(h2, v.y);
      zp[c*4+2] = __builtin_bit_cast(h2, v.z);
      zp[c*4+3] = __builtin_bit_cast(h2, v.w);
    }
    // row max: packed tree then cross-lane (4 levels within 16-lane group)
    h2 m2 = zp[0];
    #pragma unroll
    for (int t=1;t<32;++t) m2 = __builtin_elementwise_max(m2, zp[t]);
    float mx = fmaxf((float)m2.x, (float)m2.y);
    #pragma unroll
    for (int off=8; off>=1; off>>=1) mx = fmaxf(mx, __shfl_xor(mx, off));

    // safeguarded Newton on f(tau) = sum (z-tau)_+^2 - 1, root in [mx-1, mx]
    float lo = mx - 1.0f, hi = mx, tau = mx - 0.5f;
    const h2 zero2 = (h2)(f16)0;
    #pragma unroll 1
    for (int it=0; it<8; ++it){
      f16 th = (f16)tau;
      h2 t2; t2.x = th; t2.y = th;
      h2 s1h = zero2, s2h = zero2;
      #pragma unroll
      for (int t=0;t<32;++t){
        h2 d = __builtin_elementwise_max(zp[t] - t2, zero2);
        s1h = s1h + d;
        s2h = s2h + d*d;
      }
      float s1 = (float)s1h.x + (float)s1h.y;
      float s2 = (float)s2h.x + (float)s2h.y;
      #pragma unroll
      for (int off=8; off>=1; off>>=1){
        s1 += __shfl_xor(s1, off);
        s2 += __shfl_xor(s2, off);
      }
      if (s2 >= 1.0f) lo = tau; else hi = tau;
      float t2n = tau + (s2 - 1.0f)/(2.0f*s1);
      tau = (t2n >= lo && t2n < hi) ? t2n : 0.5f*(lo+hi);
    }

    // p = (z-tau)_+^2 (packed), renormalize in packed f16, write back to same slots
    {
      f16 th = (f16)tau;
      h2 t2; t2.x = th; t2.y = th;
      h2 accp = zero2;
      #pragma unroll
      for (int t=0;t<32;++t){
        h2 d = __builtin_elementwise_max(zp[t] - t2, zero2);
        h2 p = d*d;
        zp[t] = p;
        accp = accp + p;
      }
      float ps = (float)accp.x + (float)accp.y;
      #pragma unroll
      for (int off=8; off>=1; off>>=1) ps += __shfl_xor(ps, off);
      float inv = 1.0f/ps;
      f16 ih = (f16)inv;
      h2 i2; i2.x = ih; i2.y = ih;
      #pragma unroll
      for (int c=0;c<8;++c){
        uint4 vv;
        vv.x = __builtin_bit_cast(u32, (h2)(zp[c*4+0]*i2));
        vv.y = __builtin_bit_cast(u32, (h2)(zp[c*4+1]*i2));
        vv.z = __builtin_bit_cast(u32, (h2)(zp[c*4+2]*i2));
        vv.w = __builtin_bit_cast(u32, (h2)(zp[c*4+3]*i2));
        *(uint4*)(&S[r*1024 + ((r16*64 + c*8) ^ (ccb<<3))]) = vv;
      }
    }
  }
  __syncthreads();

  // ---- Phase C: ctx = P @ V ; wave w -> q-tile (w>>2), d-tile (w&3)
  const int qi = w>>2, di = w&3;
  const u16* vrow = Vt + (size_t)bh*DH*LL + (size_t)(di*16 + r16)*LL;
  f32x4 o0 = {}, o1 = {};
  const int prow = qi*16 + r16;
  #pragma unroll 8
  for (int kt=0; kt<32; ++kt){
    int k = kt*32 + g*8;
    int ccc = ((k>>6)&7) ^ (prow&7);
    f16x8 pa = *(const f16x8*)(&S[prow*1024 + (k ^ (ccc<<3))]);
    f16x8 vb = *(const f16x8*)(vrow + k);
    if (kt & 1) o1 = mfma16h(pa, vb, o1);
    else        o0 = mfma16h(pa, vb, o0);
  }
  #pragma unroll
  for (int r=0;r<4;++r){
    int q = q0 + qi*16 + g*4 + r;
    ctx[(size_t)(b*LL + q)*DM + h*DH + di*16 + r16] = f2h(o0[r] + o1[r]);
  }
}

// ---------------- launch ----------------
extern "C" void kernel_launch(void* const* d_in, const int* in_sizes, int n_in,
                              void* d_out, int out_size, void* d_ws, size_t ws_size,
                              hipStream_t stream) {
  const float* query = (const float*)d_in[0];
  const float* key   = (const float*)d_in[1];
  const float* value = (const float*)d_in[2];
  const unsigned char* maskp = (const unsigned char*)d_in[3];
  const float* q_w = (const float*)d_in[4];
  const float* q_b = (const float*)d_in[5];
  const float* k_w = (const float*)d_in[6];
  const float* k_b = (const float*)d_in[7];
  const float* v_w = (const float*)d_in[8];
  const float* v_b = (const float*)d_in[9];
  const float* out_w = (const float*)d_in[10];
  const float* out_b = (const float*)d_in[11];
  float* out = (float*)d_out;

  u16* qx = (u16*)d_ws;                 // 4M elems each
  u16* kx = qx + 4194304;
  u16* vx = kx + 4194304;
  u16* wq = vx + 4194304;               // 256K elems each
  u16* wk = wq + 262144;
  u16* wv = wk + 262144;
  u16* wo = wv + 262144;
  u16* Qp = wo + 262144;                // 4M elems each
  u16* Kp = Qp + 4194304;
  u16* Vt = Kp + 4194304;
  u16* ctx = Vt + 4194304;

  CvtArgs ca;
  ca.src[0]=query; ca.dst[0]=qx; ca.n4[0]=BB*LL*DM/4;
  ca.src[1]=key;   ca.dst[1]=kx; ca.n4[1]=BB*LL*DM/4;
  ca.src[2]=value; ca.dst[2]=vx; ca.n4[2]=BB*LL*DM/4;
  ca.src[3]=q_w;   ca.dst[3]=wq; ca.n4[3]=DM*DM/4;
  ca.src[4]=k_w;   ca.dst[4]=wk; ca.n4[4]=DM*DM/4;
  ca.src[5]=v_w;   ca.dst[5]=wv; ca.n4[5]=DM*DM/4;
  ca.src[6]=out_w; ca.dst[6]=wo; ca.n4[6]=DM*DM/4;
  cvt_kernel<<<dim3(512,7),256,0,stream>>>(ca);

  // scale = 1/16 folded into Q projection: scores = (q/16)·k = (q·k)/8/2
  gemm128<<<dim3(64,4),256,0,stream>>>(qx, wq, q_b, Qp, nullptr, 0, 0.0625f);
  gemm128<<<dim3(64,4),256,0,stream>>>(kx, wk, k_b, Kp, nullptr, 0, 1.0f);
  gemm128<<<dim3(64,4),256,0,stream>>>(vx, wv, v_b, Vt, nullptr, 1, 1.0f);

  attn_entmax<<<dim3(32,64),512,0,stream>>>(Qp, Kp, Vt, maskp, ctx);

  gemm128<<<dim3(64,4),256,0,stream>>>(ctx, wo, out_b, nullptr, out, 2, 1.0f);
}

// Round 4
// 248.398 us; speedup vs baseline: 2.0038x; 1.0183x over previous
//
#include <hip/hip_runtime.h>
#include <stdint.h>

typedef _Float16 f16;
typedef __attribute__((ext_vector_type(8))) f16 f16x8;
typedef __attribute__((ext_vector_type(2))) f16 h2;
typedef __attribute__((ext_vector_type(4))) float f32x4;
typedef unsigned short u16;
typedef unsigned int u32;
typedef unsigned char u8;

#define LL 1024
#define DM 512

__device__ __forceinline__ u16 f2h(float f){ return __builtin_bit_cast(u16, (f16)f); }
__device__ __forceinline__ u32 pack2(float a, float b){
  h2 v; v.x = (f16)a; v.y = (f16)b; return __builtin_bit_cast(u32, v);
}
__device__ __forceinline__ f32x4 mfma16h(f16x8 a, f16x8 b, f32x4 c){
  return __builtin_amdgcn_mfma_f32_16x16x32_f16(a, b, c, 0, 0, 0);
}

// ---------------- fp32 -> f16 convert ----------------
struct CvtArgs {
  const float* src[7];
  u16* dst[7];
  int n4[7];
};

__global__ __launch_bounds__(256) void cvt_kernel(CvtArgs a){
  int seg = blockIdx.y;
  const float4* s = (const float4*)a.src[seg];
  ushort4* d = (ushort4*)a.dst[seg];
  int n4 = a.n4[seg];
  for (int i = blockIdx.x*blockDim.x + threadIdx.x; i < n4; i += gridDim.x*blockDim.x){
    float4 v = s[i];
    ushort4 o;
    o.x = f2h(v.x); o.y = f2h(v.y); o.z = f2h(v.z); o.w = f2h(v.w);
    d[i] = o;
  }
}

// ---------------- projection GEMM, 128x128 tile, BK=64 ----------------
// MODE 0: QK fused (blockIdx.y>>2 selects q/k); swapped operands -> lane holds
//         4 consecutive cols -> b64 f16 stores row-major [8192][512]; (x@W+b)*scale
// MODE 1: V; original operands -> lane holds 4 consecutive rows(keys) -> b64
//         stores into Vt [b][h][64][1024]
// MODE 2: out-proj; swapped -> float4 fp32 stores [8192][512]
template<int MODE>
__global__ __launch_bounds__(256,2) void proj_gemm(
    const u16* __restrict__ A0, const u16* __restrict__ A1,
    const u16* __restrict__ W0, const u16* __restrict__ W1,
    const float* __restrict__ b0, const float* __restrict__ b1,
    u16* __restrict__ dh0, u16* __restrict__ dh1,
    float* __restrict__ dstf, float s0, float s1)
{
  __shared__ u16 As[128*64];
  __shared__ u16 Bs[128*64];
  const int tid = threadIdx.x;
  const int w = tid>>6, lane = tid&63;
  const int g = lane>>4, r16 = lane&15;
  const int wr = w>>1, wc = w&1;

  int sel, nt;
  if (MODE == 0){ sel = blockIdx.y>>2; nt = blockIdx.y&3; }
  else { sel = 0; nt = blockIdx.y; }
  const u16* A = sel ? A1 : A0;
  const u16* W = sel ? W1 : W0;
  const float* bias = sel ? b1 : b0;
  u16* dsth = sel ? dh1 : dh0;
  const float scale = sel ? s1 : s0;

  const int m0 = blockIdx.x*128, n0 = nt*128;

  f32x4 acc[4][4] = {};

  int rowc[4], slotc[4];
  #pragma unroll
  for (int i=0;i<4;++i){ int c = i*256+tid; rowc[i]=c>>3; slotc[i]=c&7; }

  uint4 ra[4], rb[4];
  #pragma unroll
  for (int i=0;i<4;++i){
    ra[i] = *(const uint4*)(A + (size_t)(m0+rowc[i])*DM + slotc[i]*8);
    rb[i] = *(const uint4*)(W + (size_t)(n0+rowc[i])*DM + slotc[i]*8);
  }

  const int fswz = r16 & 7;

  for (int k0=0; k0<DM; k0+=64){
    __syncthreads();
    #pragma unroll
    for (int i=0;i<4;++i){
      *(uint4*)(&As[rowc[i]*64 + (slotc[i]^(rowc[i]&7))*8]) = ra[i];
      *(uint4*)(&Bs[rowc[i]*64 + (slotc[i]^(rowc[i]&7))*8]) = rb[i];
    }
    __syncthreads();
    int kn = (k0+64 < DM) ? (k0+64) : 0;
    #pragma unroll
    for (int i=0;i<4;++i){
      ra[i] = *(const uint4*)(A + (size_t)(m0+rowc[i])*DM + kn + slotc[i]*8);
      rb[i] = *(const uint4*)(W + (size_t)(n0+rowc[i])*DM + kn + slotc[i]*8);
    }
    f16x8 af[4][2], bfr[4][2];
    #pragma unroll
    for (int mi=0; mi<4; ++mi){
      int row = wr*64 + mi*16 + r16;
      #pragma unroll
      for (int ks=0; ks<2; ++ks)
        af[mi][ks] = *(const f16x8*)(&As[row*64 + ((ks*4+g)^fswz)*8]);
    }
    #pragma unroll
    for (int ni=0; ni<4; ++ni){
      int row = wc*64 + ni*16 + r16;
      #pragma unroll
      for (int ks=0; ks<2; ++ks)
        bfr[ni][ks] = *(const f16x8*)(&Bs[row*64 + ((ks*4+g)^fswz)*8]);
    }
    #pragma unroll
    for (int mi=0; mi<4; ++mi)
      #pragma unroll
      for (int ni=0; ni<4; ++ni){
        if (MODE == 1){
          acc[mi][ni] = mfma16h(af[mi][0], bfr[ni][0], acc[mi][ni]);
          acc[mi][ni] = mfma16h(af[mi][1], bfr[ni][1], acc[mi][ni]);
        } else {
          acc[mi][ni] = mfma16h(bfr[ni][0], af[mi][0], acc[mi][ni]);
          acc[mi][ni] = mfma16h(bfr[ni][1], af[mi][1], acc[mi][ni]);
        }
      }
  }

  #pragma unroll
  for (int mi=0; mi<4; ++mi){
    #pragma unroll
    for (int ni=0; ni<4; ++ni){
      f32x4 a = acc[mi][ni];
      if (MODE == 1){
        // original: reg r -> 4 consecutive rows m (keys); col = n (r16)
        int mb = m0 + wr*64 + mi*16 + g*4;
        int n  = n0 + wc*64 + ni*16 + r16;
        float bv = bias[n];
        int hh = n>>6, d = n&63, bb = mb>>10, key = mb&1023;
        uint2 pk;
        pk.x = pack2(a[0]+bv, a[1]+bv);
        pk.y = pack2(a[2]+bv, a[3]+bv);
        *(uint2*)(dsth + (size_t)((bb*8+hh)*64 + d)*1024 + key) = pk;
      } else {
        // swapped: reg r -> 4 consecutive cols n; row m = r16
        int m  = m0 + wr*64 + mi*16 + r16;
        int nb = n0 + wc*64 + ni*16 + g*4;
        float4 bv = *(const float4*)(bias + nb);
        if (MODE == 0){
          uint2 pk;
          pk.x = pack2((a[0]+bv.x)*scale, (a[1]+bv.y)*scale);
          pk.y = pack2((a[2]+bv.z)*scale, (a[3]+bv.w)*scale);
          *(uint2*)(dsth + (size_t)m*DM + nb) = pk;
        } else {
          float4 o;
          o.x = a[0]+bv.x; o.y = a[1]+bv.y; o.z = a[2]+bv.z; o.w = a[3]+bv.w;
          *(float4*)(dstf + (size_t)m*DM + nb) = o;
        }
      }
    }
  }
}

// ---------------- fused attention + entmax-1.5 ----------------
// grid 4096 (1D): bh = ((bid&7)<<3)|((bid>>3)&7) clusters each bh's 64 q-blocks
// on one XCD (K/V L2-resident). 16 q-rows/block, 8 waves, 36 KiB LDS.
// S[16][1024] f16; swizzle: (row,k) at u16 off row*1024 + (k ^ (cc<<3)),
// cc = ((k>>6)&7) ^ (row&7).
__global__ __launch_bounds__(512,6) void attn_entmax(
    const u16* __restrict__ Qf, const u16* __restrict__ Kf,
    const u16* __restrict__ Vt, const u8* __restrict__ mask,
    u16* __restrict__ ctx)
{
  __shared__ u16 S[16*1024];    // 32 KiB
  __shared__ float P2[1024];    // 4 KiB phase-C partials

  const int tid = threadIdx.x, w = tid>>6, lane = tid&63;
  const int g = lane>>4, r16 = lane&15;
  const int bid = blockIdx.x;
  const int bh = ((bid&7)<<3) | ((bid>>3)&7);
  const int qb = bid>>6;
  const int b = bh>>3, h = bh&7;
  const int q0 = qb*16;
  const u16* Qb = Qf + ((size_t)(b*LL + q0))*DM + h*64;
  const u16* Kb = Kf + ((size_t)(b*LL))*DM + h*64;

  // ---- Phase A: S^T = K Q^T (scale pre-folded into Q). Wave w: keys [w*128,+128)
  f16x8 qf0 = *(const f16x8*)(Qb + r16*DM + g*8);
  f16x8 qf1 = *(const f16x8*)(Qb + r16*DM + 32 + g*8);
  #pragma unroll
  for (int kt=0; kt<8; ++kt){
    int krow = w*128 + kt*16;
    const u16* kp = Kb + (size_t)(krow + r16)*DM + g*8;
    f16x8 kf0 = *(const f16x8*)(kp);
    f16x8 kf1 = *(const f16x8*)(kp + 32);
    f32x4 acc = {};
    acc = mfma16h(kf0, qf0, acc);   // out: row=key, col=q
    acc = mfma16h(kf1, qf1, acc);
    int kb = krow + g*4;            // 4 consecutive keys per lane, q = r16
    u32 m4 = *(const u32*)(mask + b*LL + kb);
    float v0 = (m4 & 0xFFu)       ? -30000.f : acc[0];
    float v1 = (m4 & 0xFF00u)     ? -30000.f : acc[1];
    float v2 = (m4 & 0xFF0000u)   ? -30000.f : acc[2];
    float v3 = (m4 & 0xFF000000u) ? -30000.f : acc[3];
    int cc = ((kb>>6)&7) ^ (r16&7);
    uint2 pk; pk.x = pack2(v0,v1); pk.y = pack2(v2,v3);
    *(uint2*)(&S[r16*LL + (kb ^ (cc<<3))]) = pk;
  }
  __syncthreads();

  // ---- Phase B: entmax-1.5; row = 2w + (lane>>5), 32 keys/lane (16 h2 regs)
  {
    const int row = 2*w + (lane>>5);
    const int l32 = lane&31;
    int offs[4];
    h2 zp[16];
    #pragma unroll
    for (int c=0;c<4;++c){
      int kb = l32*32 + c*8;
      int cc = ((kb>>6)&7) ^ (row&7);
      offs[c] = row*LL + (kb ^ (cc<<3));
      uint4 v = *(const uint4*)(&S[offs[c]]);
      zp[c*4+0] = __builtin_bit_cast(h2, v.x);
      zp[c*4+1] = __builtin_bit_cast(h2, v.y);
      zp[c*4+2] = __builtin_bit_cast(h2, v.z);
      zp[c*4+3] = __builtin_bit_cast(h2, v.w);
    }
    h2 m2 = zp[0];
    #pragma unroll
    for (int t=1;t<16;++t) m2 = __builtin_elementwise_max(m2, zp[t]);
    float mx = fmaxf((float)m2.x, (float)m2.y);
    #pragma unroll
    for (int off=16; off>=1; off>>=1) mx = fmaxf(mx, __shfl_xor(mx, off));

    const h2 zero2 = (h2)(f16)0;
    float lo = mx - 1.0f, hi = mx, tau = mx - 0.5f;
    #pragma unroll 1
    for (int it=0; it<8; ++it){
      f16 th = (f16)tau;
      h2 t2; t2.x = th; t2.y = th;
      h2 s1h = zero2, s2h = zero2;
      #pragma unroll
      for (int t=0;t<16;++t){
        h2 d = __builtin_elementwise_max(zp[t] - t2, zero2);
        s1h = s1h + d;
        s2h = s2h + d*d;
      }
      float s1 = (float)s1h.x + (float)s1h.y;
      float s2 = (float)s2h.x + (float)s2h.y;
      #pragma unroll
      for (int off=16; off>=1; off>>=1){
        s1 += __shfl_xor(s1, off);
        s2 += __shfl_xor(s2, off);
      }
      if (s2 >= 1.0f) lo = tau; else hi = tau;
      float tn = tau + (s2 - 1.0f)/(2.0f*s1);
      tau = (tn >= lo && tn < hi) ? tn : 0.5f*(lo+hi);
    }

    {
      f16 th = (f16)tau;
      h2 t2; t2.x = th; t2.y = th;
      h2 ps2 = zero2;
      #pragma unroll
      for (int t=0;t<16;++t){
        h2 d = __builtin_elementwise_max(zp[t] - t2, zero2);
        h2 p = d*d;
        zp[t] = p;
        ps2 = ps2 + p;
      }
      float ps = (float)ps2.x + (float)ps2.y;
      #pragma unroll
      for (int off=16; off>=1; off>>=1) ps += __shfl_xor(ps, off);
      f16 iv = (f16)(1.0f/ps);
      h2 i2; i2.x = iv; i2.y = iv;
      #pragma unroll
      for (int c=0;c<4;++c){
        uint4 v;
        v.x = __builtin_bit_cast(u32, (h2)(zp[c*4+0]*i2));
        v.y = __builtin_bit_cast(u32, (h2)(zp[c*4+1]*i2));
        v.z = __builtin_bit_cast(u32, (h2)(zp[c*4+2]*i2));
        v.w = __builtin_bit_cast(u32, (h2)(zp[c*4+3]*i2));
        *(uint4*)(&S[offs[c]]) = v;    // same slots this lane read
      }
    }
  }
  __syncthreads();

  // ---- Phase C: ctx = P @ V ; wave w: d-tile (w&3), key-half (w>>2)
  const int di = w&3, kh = w>>2;
  const u16* vrow = Vt + (size_t)(bh*64 + di*16 + r16)*LL + kh*512;
  f32x4 o0 = {}, o1 = {};
  #pragma unroll
  for (int ks=0; ks<16; ++ks){
    int key = kh*512 + ks*32 + g*8;
    int cc = ((key>>6)&7) ^ (r16&7);
    f16x8 pa = *(const f16x8*)(&S[r16*LL + (key ^ (cc<<3))]);
    f16x8 vb = *(const f16x8*)(vrow + ks*32 + g*8);
    if (ks&1) o1 = mfma16h(pa, vb, o1);
    else      o0 = mfma16h(pa, vb, o0);
  }
  float o[4];
  #pragma unroll
  for (int r=0;r<4;++r) o[r] = o0[r] + o1[r];
  if (kh == 1){
    #pragma unroll
    for (int r=0;r<4;++r) P2[(di*16 + g*4 + r)*16 + r16] = o[r];
  }
  __syncthreads();
  if (kh == 0){
    u16* cp = ctx + (size_t)(b*LL + q0)*DM + h*64 + di*16 + r16;
    #pragma unroll
    for (int r=0;r<4;++r){
      float s = o[r] + P2[(di*16 + g*4 + r)*16 + r16];
      cp[(size_t)(g*4+r)*DM] = f2h(s);
    }
  }
}

// ---------------- launch ----------------
extern "C" void kernel_launch(void* const* d_in, const int* in_sizes, int n_in,
                              void* d_out, int out_size, void* d_ws, size_t ws_size,
                              hipStream_t stream) {
  const float* query = (const float*)d_in[0];
  const float* key   = (const float*)d_in[1];
  const float* value = (const float*)d_in[2];
  const u8*    maskp = (const u8*)d_in[3];
  const float* q_w = (const float*)d_in[4];
  const float* q_b = (const float*)d_in[5];
  const float* k_w = (const float*)d_in[6];
  const float* k_b = (const float*)d_in[7];
  const float* v_w = (const float*)d_in[8];
  const float* v_b = (const float*)d_in[9];
  const float* out_w = (const float*)d_in[10];
  const float* out_b = (const float*)d_in[11];
  float* out = (float*)d_out;

  u16* qx = (u16*)d_ws;                 // 4M elems each
  u16* kx = qx + 4194304;
  u16* vx = kx + 4194304;
  u16* wq = vx + 4194304;               // 256K elems each
  u16* wk = wq + 262144;
  u16* wv = wk + 262144;
  u16* wo = wv + 262144;
  u16* Qbuf = wo + 262144;              // 4M elems each
  u16* Kbuf = Qbuf + 4194304;
  u16* Vt   = Kbuf + 4194304;
  u16* ctxb = Vt + 4194304;

  CvtArgs ca;
  ca.src[0]=query; ca.dst[0]=qx; ca.n4[0]=8*LL*DM/4;
  ca.src[1]=key;   ca.dst[1]=kx; ca.n4[1]=8*LL*DM/4;
  ca.src[2]=value; ca.dst[2]=vx; ca.n4[2]=8*LL*DM/4;
  ca.src[3]=q_w;   ca.dst[3]=wq; ca.n4[3]=DM*DM/4;
  ca.src[4]=k_w;   ca.dst[4]=wk; ca.n4[4]=DM*DM/4;
  ca.src[5]=v_w;   ca.dst[5]=wv; ca.n4[5]=DM*DM/4;
  ca.src[6]=out_w; ca.dst[6]=wo; ca.n4[6]=DM*DM/4;
  cvt_kernel<<<dim3(512,7),256,0,stream>>>(ca);

  // Q (scale 1/16 folded) + K fused
  proj_gemm<0><<<dim3(64,8),256,0,stream>>>(qx,kx, wq,wk, q_b,k_b,
                                            Qbuf,Kbuf, nullptr, 0.0625f, 1.0f);
  // V -> Vt [b][h][64][1024]
  proj_gemm<1><<<dim3(64,4),256,0,stream>>>(vx,nullptr, wv,nullptr, v_b,nullptr,
                                            Vt,nullptr, nullptr, 1.0f, 1.0f);

  attn_entmax<<<dim3(4096),512,0,stream>>>(Qbuf, Kbuf, Vt, maskp, ctxb);

  // out-projection (fp32 out)
  proj_gemm<2><<<dim3(64,4),256,0,stream>>>(ctxb,nullptr, wo,nullptr, out_b,nullptr,
                                            nullptr,nullptr, out, 1.0f, 1.0f);
}